// Round 11
// baseline (270.105 us; speedup 1.0000x reference)
//
#include <hip/hip_runtime.h>

#define NVERT 6890
#define NFACE 13776
#define SS 256
#define NPIX (SS*SS)
#define TILE 8
#define NTX (SS/TILE)         // 32 tiles per row
#define NSB 256               // superblocks: 2x2 tiles each (16x16 px)
#define SPLIT 8               // face-stream segments per superblock
#define SEGLEN 1722           // NFACE / SPLIT (exact)
#define SENTINEL 0x7F800000FFFFFFFFULL   // zp=+inf, face=0xFFFFFFFF

// ws layout (byte offsets) — total ~1.49 MB (< 2.09 MB proven safe in round 1)
#define OFF_KEYS 0u           // keys: NPIX*8 = 524,288
#define OFF_VB   524288u      // vb: NVERT*3*4 = 82,680
#define OFF_FD   607232u      // fd: NFACE*16*4 = 881,664 -> ends at 1,488,896

// ---- exact-rounding helpers (no FMA contraction on the decision path) ----
static __device__ __forceinline__ float edgef(float ax, float ay, float bx, float by,
                                              float px, float py) {
  return __fsub_rn(__fmul_rn(__fsub_rn(ax, px), __fsub_rn(by, py)),
                   __fmul_rn(__fsub_rn(ay, py), __fsub_rn(bx, px)));
}

// vb layout: per vertex [sx, sy, cz]
__global__ __launch_bounds__(256) void vert_k(const float* __restrict__ cam,
                                              const float* __restrict__ verts,
                                              float* __restrict__ vb) {
  int i = blockIdx.x * 256 + threadIdx.x;
  if (i >= NVERT) return;
  float c0 = cam[0], c1 = cam[1], c2 = cam[2];
  float vx = verts[i*3+0], vy = verts[i*3+1], vz = verts[i*3+2];
  vb[i*3+0] = __fmul_rn(c0, __fadd_rn(vx, c1));
  vb[i*3+1] = __fmul_rn(c0, __fadd_rn(vy, c2));
  vb[i*3+2] = __fadd_rn(vz, 2.7320508075688776f);
}

__global__ __launch_bounds__(256) void init_k(unsigned long long* __restrict__ keys) {
  int p = blockIdx.x * 256 + threadIdx.x;
  if (p < NPIX) keys[p] = SENTINEL;
}

// texture sampling: one thread per (face, sample t in 0..8); writes out_tex only
__global__ __launch_bounds__(256) void tex_k(const float* __restrict__ vb,
                                             const int* __restrict__ faces,
                                             const float* __restrict__ uv,
                                             float* __restrict__ out_tex) {
  int tid = blockIdx.x * 256 + threadIdx.x;
  if (tid >= NFACE * 9) return;
  int f = tid / 9, t = tid - f * 9;
  int ti = t / 3, tj = t - ti * 3;
  float xt = 0.5f * (float)ti;
  float yt = 0.5f * (float)tj;
  int ia = faces[f*3+0], ib = faces[f*3+1], ic = faces[f*3+2];
  float ax = vb[ia*3+0], ay = vb[ia*3+1];
  float bx = vb[ib*3+0], by = vb[ib*3+1];
  float cx = vb[ic*3+0], cy = vb[ic*3+1];
  float sx = (ax - cx) * xt + (bx - cx) * yt + cx;
  float sy = (ay - cy) * xt + (by - cy) * yt + cy;
  sx = fminf(fmaxf(sx, -1.f), 1.f);
  sy = fminf(fmaxf(sy, -1.f), 1.f);
  float gx = (sx + 1.f) * 128.f - 0.5f;
  float gy = (sy + 1.f) * 128.f - 0.5f;
  float x0f = floorf(gx), y0f = floorf(gy);
  float fx = gx - x0f, fy = gy - y0f;
  int x0 = (int)x0f, y0 = (int)y0f;
  float r = 0.f, g = 0.f, b = 0.f;
  #pragma unroll
  for (int dy = 0; dy < 2; ++dy) {
    #pragma unroll
    for (int dx = 0; dx < 2; ++dx) {
      int xi = x0 + dx, yi = y0 + dy;
      if (xi >= 0 && xi < SS && yi >= 0 && yi < SS) {
        float w = (dx ? fx : 1.f - fx) * (dy ? fy : 1.f - fy);
        int base = yi * SS + xi;
        r += w * uv[base];
        g += w * uv[NPIX + base];
        b += w * uv[2 * NPIX + base];
      }
    }
  }
  float* ot = out_tex + f * 81 + ti * 27 + tj * 9;
  #pragma unroll
  for (int kk = 0; kk < 3; ++kk) {
    ot[kk*3+0] = r; ot[kk*3+1] = g; ot[kk*3+2] = b;
  }
}

// per-face setup: 64B record; tilepack now in 8-px tile coords (0..31)
__global__ __launch_bounds__(256) void setup_k(const float* __restrict__ vb,
                                               const int* __restrict__ faces,
                                               float* __restrict__ fd) {
  int f = blockIdx.x * 256 + threadIdx.x;
  if (f >= NFACE) return;
  float* fp = fd + (size_t)f * 16;
  int ia = faces[f*3+0], ib = faces[f*3+1], ic = faces[f*3+2];
  float x0 = vb[ia*3+0], y0 = -vb[ia*3+1], z0 = vb[ia*3+2];
  float x1 = vb[ib*3+0], y1 = -vb[ib*3+1], z1 = vb[ib*3+2];
  float x2 = vb[ic*3+0], y2 = -vb[ic*3+1], z2 = vb[ic*3+2];
  float det = edgef(x1, y1, x2, y2, x0, y0);
  unsigned int tilepack = 0x000000FFu;                   // tx0=255 > tx1=0 -> never overlaps
  if (det > 1e-10f) {
    float mnx = fminf(x0, fminf(x1, x2)), mxx = fmaxf(x0, fmaxf(x1, x2));
    float mny = fminf(y0, fminf(y1, y2)), mxy = fmaxf(y0, fmaxf(y1, y2));
    int xlo = max((int)floorf((mnx * 256.f + 255.f) * 0.5f) - 2, 0);
    int xhi = min((int)ceilf ((mxx * 256.f + 255.f) * 0.5f) + 2, SS - 1);
    int ylo = max((int)floorf((mny * 256.f + 255.f) * 0.5f) - 2, 0);
    int yhi = min((int)ceilf ((mxy * 256.f + 255.f) * 0.5f) + 2, SS - 1);
    if (xlo <= xhi && ylo <= yhi)
      tilepack = (unsigned int)(xlo >> 3) | ((unsigned int)(ylo >> 3) << 8)
               | ((unsigned int)(xhi >> 3) << 16) | ((unsigned int)(yhi >> 3) << 24);
  }
  float rz0 = (fabsf(z0) > 1e-8f) ? z0 : 1.0f;
  float rz1 = (fabsf(z1) > 1e-8f) ? z1 : 1.0f;
  float rz2 = (fabsf(z2) > 1e-8f) ? z2 : 1.0f;
  float minrz = fminf(fminf(fabsf(rz0), fabsf(rz1)), fabsf(rz2));
  unsigned int flag = (minrz < 0.05f) ? 1u : 0u;
  fp[0] = x0;  fp[1] = y0;  fp[2] = x1;  fp[3] = y1;
  fp[4] = x2;  fp[5] = y2;  fp[6] = rz0; fp[7] = rz1;
  fp[8] = rz2; fp[9] = det;
  fp[10] = __fdiv_rn(1.0f, det * rz0);                   // approx coeffs
  fp[11] = __fdiv_rn(1.0f, det * rz1);
  fp[12] = __fdiv_rn(1.0f, det * rz2);
  fp[13] = __uint_as_float((unsigned int)f | (flag << 24));
  fp[14] = __uint_as_float(tilepack);
  fp[15] = 0.f;
}

// fused bin+rasterize: block = 2x2 quad of 8x8 tiles (one wave per tile, one
// lane per pixel). tid<64 scans 64-record chunks into 4 per-wave LDS lists;
// each wave consumes its own list; z-key in registers; one atomicMin/pixel.
__global__ __launch_bounds__(256) void tile_k(const float* __restrict__ fd,
                                              unsigned long long* __restrict__ keys) {
  __shared__ float rec[4][64][15];   // 14 used + pad; 15.4 KB
  __shared__ unsigned int cnt_s[4];
  int sb  = blockIdx.x & (NSB - 1);
  int seg = blockIdx.x >> 8;         // 0..SPLIT-1
  int tid = threadIdx.x;
  int w = tid >> 6, lane = tid & 63;
  int sbx = sb & 15, sby = sb >> 4;
  int tx = sbx * 2 + (w & 1);        // this wave's 8-px tile coords (0..31)
  int ty = sby * 2 + (w >> 1);
  int xx = tx * TILE + (lane & 7);
  int yy = ty * TILE + (lane >> 3);
  float px = (float)(2 * xx + 1 - SS) * (1.0f / 256.0f);   // exact
  float py = (float)(2 * yy + 1 - SS) * (1.0f / 256.0f);
  unsigned long long best = SENTINEL;
  int fbeg = seg * SEGLEN;
  int fend = min(fbeg + SEGLEN, NFACE);

  for (int base = fbeg; base < fend; base += 64) {
    __syncthreads();                       // previous consume done
    if (tid < 4) cnt_s[tid] = 0;
    __syncthreads();
    int f = base + tid;
    if (tid < 64 && f < fend) {
      const float4* fr = (const float4*)(fd + (size_t)f * 16);
      float4 A = fr[0];                    // x0,y0,x1,y1
      float4 B = fr[1];                    // x2,y2,rz0,rz1
      float4 C = fr[2];                    // rz2,det,c0,c1
      float4 D = fr[3];                    // c2,idflag,tilepack,-
      unsigned int tp = __float_as_uint(D.z);
      int tx0 = (int)(tp & 255u),         ty0 = (int)((tp >> 8) & 255u);
      int tx1 = (int)((tp >> 16) & 255u), ty1 = (int)(tp >> 24);
      #pragma unroll
      for (int q = 0; q < 4; ++q) {
        int qtx = sbx * 2 + (q & 1);
        int qty = sby * 2 + (q >> 1);
        if (qtx >= tx0 && qtx <= tx1 && qty >= ty0 && qty <= ty1) {
          unsigned int slot = atomicAdd(&cnt_s[q], 1u);   // LDS atomic, <=64
          float* rp = rec[q][slot];
          rp[0]  = A.x; rp[1]  = A.y; rp[2]  = A.z; rp[3]  = A.w;
          rp[4]  = B.x; rp[5]  = B.y; rp[6]  = B.z; rp[7]  = B.w;
          rp[8]  = C.x; rp[9]  = C.y; rp[10] = C.z; rp[11] = C.w;
          rp[12] = D.x; rp[13] = D.y;
        }
      }
    }
    __syncthreads();
    int m = (int)cnt_s[w];
    for (int j = 0; j < m; ++j) {
      const float* rp = rec[w][j];
      float x0 = rp[0], y0 = rp[1];
      float x1 = rp[2], y1 = rp[3];
      float x2 = rp[4], y2 = rp[5];
      float e0 = edgef(x1, y1, x2, y2, px, py);
      float e1 = edgef(x2, y2, x0, y0, px, py);
      float e2 = edgef(x0, y0, x1, y1, px, py);
      if (e0 >= 0.f && e1 >= 0.f && e2 >= 0.f) {
        float inva = __fmaf_rn(e0, rp[10], __fmaf_rn(e1, rp[11], e2 * rp[12]));
        float zc = __uint_as_float((unsigned int)(best >> 32));   // local best (conservative)
        unsigned int w13 = __float_as_uint(rp[13]);
        bool pass = ((w13 >> 24) != 0u) | (inva * zc > 0.998f) | (fabsf(inva) < 1e-4f);
        if (pass) {
          // exact reference chain (bit-identical decision path)
          float rz0 = rp[6], rz1 = rp[7], rz2 = rp[8], det = rp[9];
          float b0 = __fdiv_rn(e0, det);
          float b1 = __fdiv_rn(e1, det);
          float b2 = __fdiv_rn(e2, det);
          float inv = __fadd_rn(__fadd_rn(__fdiv_rn(b0, rz0), __fdiv_rn(b1, rz1)),
                                __fdiv_rn(b2, rz2));
          if (!(fabsf(inv) > 1e-8f)) inv = 1.0f;
          float zp = __fdiv_rn(1.0f, inv);
          if (zp > 0.1f && zp < 25.0f) {
            unsigned long long key =
                ((unsigned long long)__float_as_uint(zp) << 32)
                | (w13 & 0x00FFFFFFu);
            if (key < best) best = key;
          }
        }
      }
    }
  }
  if (best != SENTINEL) {
    int p = yy * SS + xx;
    if (best < keys[p]) atomicMin(&keys[p], best);   // monotone merge
  }
}

// resolve: one thread per pixel -> images output (exact reference chain)
__global__ __launch_bounds__(256) void resolve_k(const float* __restrict__ vb,
                                                 const int* __restrict__ faces,
                                                 const unsigned long long* __restrict__ keys,
                                                 const float* __restrict__ out_tex,
                                                 float* __restrict__ out_img) {
  int p = blockIdx.x * 256 + threadIdx.x;
  if (p >= NPIX) return;
  unsigned long long k = keys[p];
  float c0 = 0.f, c1 = 0.f, c2 = 0.f;
  if (k != SENTINEL) {
    int f = (int)(unsigned int)(k & 0x00FFFFFFULL);
    float bz = __uint_as_float((unsigned int)(k >> 32));
    int xx = p & (SS - 1), yy = p >> 8;
    float px = (float)(2 * xx + 1 - SS) * (1.0f / 256.0f);
    float py = (float)(2 * yy + 1 - SS) * (1.0f / 256.0f);
    int ia = faces[f*3+0], ib = faces[f*3+1], ic = faces[f*3+2];
    float x0 = vb[ia*3+0], y0 = -vb[ia*3+1], z0 = vb[ia*3+2];
    float x1 = vb[ib*3+0], y1 = -vb[ib*3+1], z1 = vb[ib*3+2];
    float x2 = vb[ic*3+0], y2 = -vb[ic*3+1], z2 = vb[ic*3+2];
    float det = edgef(x1, y1, x2, y2, x0, y0);
    float e0 = edgef(x1, y1, x2, y2, px, py);
    float e1 = edgef(x2, y2, x0, y0, px, py);
    float e2 = edgef(x0, y0, x1, y1, px, py);
    float b0 = __fdiv_rn(e0, det);
    float b1 = __fdiv_rn(e1, det);
    float b2 = __fdiv_rn(e2, det);
    float rz0 = (fabsf(z0) > 1e-8f) ? z0 : 1.0f;
    float rz1 = (fabsf(z1) > 1e-8f) ? z1 : 1.0f;
    float rz2 = (fabsf(z2) > 1e-8f) ? z2 : 1.0f;
    float w0 = __fmul_rn(__fdiv_rn(b0, rz0), bz);
    float w1 = __fmul_rn(__fdiv_rn(b1, rz1), bz);
    float w2 = __fmul_rn(__fdiv_rn(b2, rz2), bz);
    float pos0 = fminf(fmaxf(w0, 0.f), 1.f) * 2.f;
    float pos1 = fminf(fmaxf(w1, 0.f), 1.f) * 2.f;
    float pos2 = fminf(fmaxf(w2, 0.f), 1.f) * 2.f;
    float i0f = fminf(fmaxf(floorf(pos0), 0.f), 1.f);
    float i1f = fminf(fmaxf(floorf(pos1), 0.f), 1.f);
    float i2f = fminf(fmaxf(floorf(pos2), 0.f), 1.f);
    float fr0 = fminf(fmaxf(__fsub_rn(pos0, i0f), 0.f), 1.f);
    float fr1 = fminf(fmaxf(__fsub_rn(pos1, i1f), 0.f), 1.f);
    float fr2 = fminf(fmaxf(__fsub_rn(pos2, i2f), 0.f), 1.f);
    int i00 = (int)i0f, i01 = (int)i1f;
    #pragma unroll
    for (int d0 = 0; d0 < 2; ++d0) {
      float wa = d0 ? fr0 : __fsub_rn(1.f, fr0);
      #pragma unroll
      for (int d1 = 0; d1 < 2; ++d1) {
        float wb = d1 ? fr1 : __fsub_rn(1.f, fr1);
        int a = min(i00 + d0, 2);
        int b = min(i01 + d1, 2);
        const float* tp = &out_tex[f * 81 + a * 27 + b * 9];  // k=0 slice
        float wab = __fmul_rn(wa, wb);
        #pragma unroll
        for (int d2 = 0; d2 < 2; ++d2) {
          float wc = d2 ? fr2 : __fsub_rn(1.f, fr2);
          float wgt = __fmul_rn(wab, wc);
          c0 = __fadd_rn(c0, __fmul_rn(wgt, tp[0]));
          c1 = __fadd_rn(c1, __fmul_rn(wgt, tp[1]));
          c2 = __fadd_rn(c2, __fmul_rn(wgt, tp[2]));
        }
      }
    }
  }
  out_img[p]          = c0;
  out_img[NPIX + p]   = c1;
  out_img[2*NPIX + p] = c2;
}

extern "C" void kernel_launch(void* const* d_in, const int* in_sizes, int n_in,
                              void* d_out, int out_size, void* d_ws, size_t ws_size,
                              hipStream_t stream) {
  const float* cam   = (const float*)d_in[0];
  const float* verts = (const float*)d_in[1];
  const float* uv    = (const float*)d_in[2];
  const int*   faces = (const int*)d_in[3];
  float* out_img = (float*)d_out;            // (1,3,256,256)
  float* out_tex = (float*)d_out + 3 * NPIX; // (1,NF,3,3,3,3)

  char* ws = (char*)d_ws;
  unsigned long long* keys = (unsigned long long*)(ws + OFF_KEYS);
  float* vb = (float*)(ws + OFF_VB);
  float* fd = (float*)(ws + OFF_FD);

  vert_k<<<(NVERT + 255) / 256, 256, 0, stream>>>(cam, verts, vb);
  init_k<<<NPIX / 256, 256, 0, stream>>>(keys);
  tex_k<<<(NFACE * 9 + 255) / 256, 256, 0, stream>>>(vb, faces, uv, out_tex);
  setup_k<<<(NFACE + 255) / 256, 256, 0, stream>>>(vb, faces, fd);
  tile_k<<<NSB * SPLIT, 256, 0, stream>>>(fd, keys);
  resolve_k<<<NPIX / 256, 256, 0, stream>>>(vb, faces, keys, out_tex, out_img);
}

// Round 12
// 156.058 us; speedup vs baseline: 1.7308x; 1.7308x over previous
//
#include <hip/hip_runtime.h>

#define NVERT 6890
#define NFACE 13776
#define SS 256
#define NPIX (SS*SS)
#define TILE 8
#define NSB 256               // superblocks: 2x2 tiles of 8x8 px (16x16 px)
#define SPLIT 16              // face-stream segments per superblock
#define SEGLEN 861            // NFACE / SPLIT (exact: 861*16 = 13776)
#define SENTINEL 0x7F800000FFFFFFFFULL   // zp=+inf, face=0xFFFFFFFF

// ws layout (byte offsets) — total ~1.60 MB (< 2.09 MB proven safe in round 1)
#define OFF_KEYS 0u           // keys: NPIX*8 = 524,288
#define OFF_VB   524288u      // vb: NVERT*3*4 = 82,680
#define OFF_FD   607232u      // fd: NFACE*16*4 = 881,664
#define OFF_TD   1488896u     // td: NFACE*8 = 110,208 -> ends at 1,599,104

// ---- exact-rounding helpers (no FMA contraction on the decision path) ----
static __device__ __forceinline__ float edgef(float ax, float ay, float bx, float by,
                                              float px, float py) {
  return __fsub_rn(__fmul_rn(__fsub_rn(ax, px), __fsub_rn(by, py)),
                   __fmul_rn(__fsub_rn(ay, py), __fsub_rn(bx, px)));
}

// vb layout: per vertex [sx, sy, cz]
__global__ __launch_bounds__(256) void vert_k(const float* __restrict__ cam,
                                              const float* __restrict__ verts,
                                              float* __restrict__ vb) {
  int i = blockIdx.x * 256 + threadIdx.x;
  if (i >= NVERT) return;
  float c0 = cam[0], c1 = cam[1], c2 = cam[2];
  float vx = verts[i*3+0], vy = verts[i*3+1], vz = verts[i*3+2];
  vb[i*3+0] = __fmul_rn(c0, __fadd_rn(vx, c1));
  vb[i*3+1] = __fmul_rn(c0, __fadd_rn(vy, c2));
  vb[i*3+2] = __fadd_rn(vz, 2.7320508075688776f);
}

__global__ __launch_bounds__(256) void init_k(unsigned long long* __restrict__ keys) {
  int p = blockIdx.x * 256 + threadIdx.x;
  if (p < NPIX) keys[p] = SENTINEL;
}

// texture sampling: one thread per (face, sample t in 0..8); writes out_tex only
__global__ __launch_bounds__(256) void tex_k(const float* __restrict__ vb,
                                             const int* __restrict__ faces,
                                             const float* __restrict__ uv,
                                             float* __restrict__ out_tex) {
  int tid = blockIdx.x * 256 + threadIdx.x;
  if (tid >= NFACE * 9) return;
  int f = tid / 9, t = tid - f * 9;
  int ti = t / 3, tj = t - ti * 3;
  float xt = 0.5f * (float)ti;
  float yt = 0.5f * (float)tj;
  int ia = faces[f*3+0], ib = faces[f*3+1], ic = faces[f*3+2];
  float ax = vb[ia*3+0], ay = vb[ia*3+1];
  float bx = vb[ib*3+0], by = vb[ib*3+1];
  float cx = vb[ic*3+0], cy = vb[ic*3+1];
  float sx = (ax - cx) * xt + (bx - cx) * yt + cx;
  float sy = (ay - cy) * xt + (by - cy) * yt + cy;
  sx = fminf(fmaxf(sx, -1.f), 1.f);
  sy = fminf(fmaxf(sy, -1.f), 1.f);
  float gx = (sx + 1.f) * 128.f - 0.5f;
  float gy = (sy + 1.f) * 128.f - 0.5f;
  float x0f = floorf(gx), y0f = floorf(gy);
  float fx = gx - x0f, fy = gy - y0f;
  int x0 = (int)x0f, y0 = (int)y0f;
  float r = 0.f, g = 0.f, b = 0.f;
  #pragma unroll
  for (int dy = 0; dy < 2; ++dy) {
    #pragma unroll
    for (int dx = 0; dx < 2; ++dx) {
      int xi = x0 + dx, yi = y0 + dy;
      if (xi >= 0 && xi < SS && yi >= 0 && yi < SS) {
        float w = (dx ? fx : 1.f - fx) * (dy ? fy : 1.f - fy);
        int base = yi * SS + xi;
        r += w * uv[base];
        g += w * uv[NPIX + base];
        b += w * uv[2 * NPIX + base];
      }
    }
  }
  float* ot = out_tex + f * 81 + ti * 27 + tj * 9;
  #pragma unroll
  for (int kk = 0; kk < 3; ++kk) {
    ot[kk*3+0] = r; ot[kk*3+1] = g; ot[kk*3+2] = b;
  }
}

// per-face setup: 64B record + dense 8B side-car {tilepack, zmin_bits}
// record: [x0,y0,x1,y1 | x2,y2,rz0,rz1 | rz2,det,c0,c1 | c2,idflag,tilepack,zminbits]
__global__ __launch_bounds__(256) void setup_k(const float* __restrict__ vb,
                                               const int* __restrict__ faces,
                                               float* __restrict__ fd,
                                               uint2* __restrict__ td) {
  int f = blockIdx.x * 256 + threadIdx.x;
  if (f >= NFACE) return;
  float* fp = fd + (size_t)f * 16;
  int ia = faces[f*3+0], ib = faces[f*3+1], ic = faces[f*3+2];
  float x0 = vb[ia*3+0], y0 = -vb[ia*3+1], z0 = vb[ia*3+2];
  float x1 = vb[ib*3+0], y1 = -vb[ib*3+1], z1 = vb[ib*3+2];
  float x2 = vb[ic*3+0], y2 = -vb[ic*3+1], z2 = vb[ic*3+2];
  float det = edgef(x1, y1, x2, y2, x0, y0);
  unsigned int tilepack = 0x000000FFu;                   // tx0=255 > tx1=0 -> never overlaps
  if (det > 1e-10f) {
    float mnx = fminf(x0, fminf(x1, x2)), mxx = fmaxf(x0, fmaxf(x1, x2));
    float mny = fminf(y0, fminf(y1, y2)), mxy = fmaxf(y0, fmaxf(y1, y2));
    int xlo = max((int)floorf((mnx * 256.f + 255.f) * 0.5f) - 2, 0);
    int xhi = min((int)ceilf ((mxx * 256.f + 255.f) * 0.5f) + 2, SS - 1);
    int ylo = max((int)floorf((mny * 256.f + 255.f) * 0.5f) - 2, 0);
    int yhi = min((int)ceilf ((mxy * 256.f + 255.f) * 0.5f) + 2, SS - 1);
    if (xlo <= xhi && ylo <= yhi)
      tilepack = (unsigned int)(xlo >> 3) | ((unsigned int)(ylo >> 3) << 8)
               | ((unsigned int)(xhi >> 3) << 16) | ((unsigned int)(yhi >> 3) << 24);
  }
  float rz0 = (fabsf(z0) > 1e-8f) ? z0 : 1.0f;
  float rz1 = (fabsf(z1) > 1e-8f) ? z1 : 1.0f;
  float rz2 = (fabsf(z2) > 1e-8f) ? z2 : 1.0f;
  float minrz = fminf(fminf(fabsf(rz0), fabsf(rz1)), fabsf(rz2));
  unsigned int flag = (minrz < 0.05f) ? 1u : 0u;
  // conservative z-min: for inside px, zp = 1/(sum b_i/rz_i) >= min rz_i when all
  // rz_i > 0 (harmonic-mean bound); 0.999 absorbs fp slop. 0 disables the skip.
  unsigned int zmb = 0u;
  if (flag == 0u) {
    float mn = fminf(fminf(rz0, rz1), rz2);
    if (mn > 0.f) zmb = __float_as_uint(mn * 0.999f);
  }
  fp[0] = x0;  fp[1] = y0;  fp[2] = x1;  fp[3] = y1;
  fp[4] = x2;  fp[5] = y2;  fp[6] = rz0; fp[7] = rz1;
  fp[8] = rz2; fp[9] = det;
  fp[10] = __fdiv_rn(1.0f, det * rz0);                   // approx coeffs
  fp[11] = __fdiv_rn(1.0f, det * rz1);
  fp[12] = __fdiv_rn(1.0f, det * rz2);
  fp[13] = __uint_as_float((unsigned int)f | (flag << 24));
  fp[14] = __uint_as_float(tilepack);
  fp[15] = __uint_as_float(zmb);
  td[f] = make_uint2(tilepack, zmb);
}

// fused bin+rasterize: block = 2x2 quad of 8x8 tiles (wave w owns quad w, one
// lane per pixel). All 256 threads scan the dense side-car per 256-face chunk,
// appending u16 indices to per-quad LDS lists (z-killed vs wave-max best).
// Consume: uniform record load per hit, per-lane z-skip, exact chain, reg z-key.
__global__ __launch_bounds__(256) void tile_k(const float* __restrict__ fd,
                                              const uint2* __restrict__ td,
                                              unsigned long long* __restrict__ keys) {
  __shared__ unsigned short idx_s[4][256];
  __shared__ unsigned int cnt_s[4];
  __shared__ unsigned int wmax_s[4];
  int sb  = blockIdx.x & (NSB - 1);
  int seg = blockIdx.x >> 8;         // 0..SPLIT-1
  int tid = threadIdx.x;
  int w = tid >> 6, lane = tid & 63;
  int sbx = sb & 15, sby = sb >> 4;
  int tx = sbx * 2 + (w & 1);        // this wave's 8-px tile coords (0..31)
  int ty = sby * 2 + (w >> 1);
  int xx = tx * TILE + (lane & 7);
  int yy = ty * TILE + (lane >> 3);
  float px = (float)(2 * xx + 1 - SS) * (1.0f / 256.0f);   // exact
  float py = (float)(2 * yy + 1 - SS) * (1.0f / 256.0f);
  unsigned long long best = SENTINEL;
  int fbeg = seg * SEGLEN;
  int fend = min(fbeg + SEGLEN, NFACE);

  for (int base = fbeg; base < fend; base += 256) {
    // wave-max of per-lane best z (monotone; conservative for scan-level kill)
    unsigned int bh = (unsigned int)(best >> 32);
    #pragma unroll
    for (int o = 32; o > 0; o >>= 1)
      bh = max(bh, (unsigned int)__shfl_xor((int)bh, o, 64));
    __syncthreads();                       // previous consume done
    if (lane == 0) wmax_s[w] = bh;
    if (tid < 4) cnt_s[tid] = 0;
    __syncthreads();
    int f = base + tid;
    if (f < fend) {
      uint2 t2 = td[f];
      unsigned int tp = t2.x, zmb = t2.y;
      int tx0 = (int)(tp & 255u),         ty0 = (int)((tp >> 8) & 255u);
      int tx1 = (int)((tp >> 16) & 255u), ty1 = (int)(tp >> 24);
      #pragma unroll
      for (int q = 0; q < 4; ++q) {
        int qtx = sbx * 2 + (q & 1);
        int qty = sby * 2 + (q >> 1);
        if (qtx >= tx0 && qtx <= tx1 && qty >= ty0 && qty <= ty1
            && zmb <= wmax_s[q]) {
          unsigned int slot = atomicAdd(&cnt_s[q], 1u);   // LDS atomic, <=256
          idx_s[q][slot] = (unsigned short)f;
        }
      }
    }
    __syncthreads();
    int m = (int)cnt_s[w];
    for (int j = 0; j < m; ++j) {
      int f2 = __builtin_amdgcn_readfirstlane((int)idx_s[w][j]);  // scalar addr
      const float4* fr = (const float4*)(fd + (size_t)f2 * 16);
      float4 A  = fr[0];                   // x0,y0,x1,y1
      float4 Bv = fr[1];                   // x2,y2,rz0,rz1
      float4 Cv = fr[2];                   // rz2,det,c0,c1
      float4 Dv = fr[3];                   // c2,idflag,tilepack,zminbits
      unsigned int zmb = __float_as_uint(Dv.w);
      if (zmb > (unsigned int)(best >> 32)) continue;    // per-lane z-kill (strict)
      float e0 = edgef(A.z, A.w, Bv.x, Bv.y, px, py);
      float e1 = edgef(Bv.x, Bv.y, A.x, A.y, px, py);
      float e2 = edgef(A.x, A.y, A.z, A.w, px, py);
      if (e0 >= 0.f && e1 >= 0.f && e2 >= 0.f) {
        float inva = __fmaf_rn(e0, Cv.z, __fmaf_rn(e1, Cv.w, e2 * Dv.x));
        float zc = __uint_as_float((unsigned int)(best >> 32));   // local best
        unsigned int w13 = __float_as_uint(Dv.y);
        bool pass = ((w13 >> 24) != 0u) | (inva * zc > 0.998f) | (fabsf(inva) < 1e-4f);
        if (pass) {
          // exact reference chain (bit-identical decision path)
          float rz0 = Bv.z, rz1 = Bv.w, rz2 = Cv.x, det = Cv.y;
          float b0 = __fdiv_rn(e0, det);
          float b1 = __fdiv_rn(e1, det);
          float b2 = __fdiv_rn(e2, det);
          float inv = __fadd_rn(__fadd_rn(__fdiv_rn(b0, rz0), __fdiv_rn(b1, rz1)),
                                __fdiv_rn(b2, rz2));
          if (!(fabsf(inv) > 1e-8f)) inv = 1.0f;
          float zp = __fdiv_rn(1.0f, inv);
          if (zp > 0.1f && zp < 25.0f) {
            unsigned long long key =
                ((unsigned long long)__float_as_uint(zp) << 32)
                | (w13 & 0x00FFFFFFu);
            if (key < best) best = key;
          }
        }
      }
    }
  }
  if (best != SENTINEL) {
    int p = yy * SS + xx;
    if (best < keys[p]) atomicMin(&keys[p], best);   // monotone merge
  }
}

// resolve: one thread per pixel -> images output (exact reference chain)
__global__ __launch_bounds__(256) void resolve_k(const float* __restrict__ vb,
                                                 const int* __restrict__ faces,
                                                 const unsigned long long* __restrict__ keys,
                                                 const float* __restrict__ out_tex,
                                                 float* __restrict__ out_img) {
  int p = blockIdx.x * 256 + threadIdx.x;
  if (p >= NPIX) return;
  unsigned long long k = keys[p];
  float c0 = 0.f, c1 = 0.f, c2 = 0.f;
  if (k != SENTINEL) {
    int f = (int)(unsigned int)(k & 0x00FFFFFFULL);
    float bz = __uint_as_float((unsigned int)(k >> 32));
    int xx = p & (SS - 1), yy = p >> 8;
    float px = (float)(2 * xx + 1 - SS) * (1.0f / 256.0f);
    float py = (float)(2 * yy + 1 - SS) * (1.0f / 256.0f);
    int ia = faces[f*3+0], ib = faces[f*3+1], ic = faces[f*3+2];
    float x0 = vb[ia*3+0], y0 = -vb[ia*3+1], z0 = vb[ia*3+2];
    float x1 = vb[ib*3+0], y1 = -vb[ib*3+1], z1 = vb[ib*3+2];
    float x2 = vb[ic*3+0], y2 = -vb[ic*3+1], z2 = vb[ic*3+2];
    float det = edgef(x1, y1, x2, y2, x0, y0);
    float e0 = edgef(x1, y1, x2, y2, px, py);
    float e1 = edgef(x2, y2, x0, y0, px, py);
    float e2 = edgef(x0, y0, x1, y1, px, py);
    float b0 = __fdiv_rn(e0, det);
    float b1 = __fdiv_rn(e1, det);
    float b2 = __fdiv_rn(e2, det);
    float rz0 = (fabsf(z0) > 1e-8f) ? z0 : 1.0f;
    float rz1 = (fabsf(z1) > 1e-8f) ? z1 : 1.0f;
    float rz2 = (fabsf(z2) > 1e-8f) ? z2 : 1.0f;
    float w0 = __fmul_rn(__fdiv_rn(b0, rz0), bz);
    float w1 = __fmul_rn(__fdiv_rn(b1, rz1), bz);
    float w2 = __fmul_rn(__fdiv_rn(b2, rz2), bz);
    float pos0 = fminf(fmaxf(w0, 0.f), 1.f) * 2.f;
    float pos1 = fminf(fmaxf(w1, 0.f), 1.f) * 2.f;
    float pos2 = fminf(fmaxf(w2, 0.f), 1.f) * 2.f;
    float i0f = fminf(fmaxf(floorf(pos0), 0.f), 1.f);
    float i1f = fminf(fmaxf(floorf(pos1), 0.f), 1.f);
    float i2f = fminf(fmaxf(floorf(pos2), 0.f), 1.f);
    float fr0 = fminf(fmaxf(__fsub_rn(pos0, i0f), 0.f), 1.f);
    float fr1 = fminf(fmaxf(__fsub_rn(pos1, i1f), 0.f), 1.f);
    float fr2 = fminf(fmaxf(__fsub_rn(pos2, i2f), 0.f), 1.f);
    int i00 = (int)i0f, i01 = (int)i1f;
    #pragma unroll
    for (int d0 = 0; d0 < 2; ++d0) {
      float wa = d0 ? fr0 : __fsub_rn(1.f, fr0);
      #pragma unroll
      for (int d1 = 0; d1 < 2; ++d1) {
        float wb = d1 ? fr1 : __fsub_rn(1.f, fr1);
        int a = min(i00 + d0, 2);
        int b = min(i01 + d1, 2);
        const float* tp = &out_tex[f * 81 + a * 27 + b * 9];  // k=0 slice
        float wab = __fmul_rn(wa, wb);
        #pragma unroll
        for (int d2 = 0; d2 < 2; ++d2) {
          float wc = d2 ? fr2 : __fsub_rn(1.f, fr2);
          float wgt = __fmul_rn(wab, wc);
          c0 = __fadd_rn(c0, __fmul_rn(wgt, tp[0]));
          c1 = __fadd_rn(c1, __fmul_rn(wgt, tp[1]));
          c2 = __fadd_rn(c2, __fmul_rn(wgt, tp[2]));
        }
      }
    }
  }
  out_img[p]          = c0;
  out_img[NPIX + p]   = c1;
  out_img[2*NPIX + p] = c2;
}

extern "C" void kernel_launch(void* const* d_in, const int* in_sizes, int n_in,
                              void* d_out, int out_size, void* d_ws, size_t ws_size,
                              hipStream_t stream) {
  const float* cam   = (const float*)d_in[0];
  const float* verts = (const float*)d_in[1];
  const float* uv    = (const float*)d_in[2];
  const int*   faces = (const int*)d_in[3];
  float* out_img = (float*)d_out;            // (1,3,256,256)
  float* out_tex = (float*)d_out + 3 * NPIX; // (1,NF,3,3,3,3)

  char* ws = (char*)d_ws;
  unsigned long long* keys = (unsigned long long*)(ws + OFF_KEYS);
  float* vb = (float*)(ws + OFF_VB);
  float* fd = (float*)(ws + OFF_FD);
  uint2* td = (uint2*)(ws + OFF_TD);

  vert_k<<<(NVERT + 255) / 256, 256, 0, stream>>>(cam, verts, vb);
  init_k<<<NPIX / 256, 256, 0, stream>>>(keys);
  tex_k<<<(NFACE * 9 + 255) / 256, 256, 0, stream>>>(vb, faces, uv, out_tex);
  setup_k<<<(NFACE + 255) / 256, 256, 0, stream>>>(vb, faces, fd, td);
  tile_k<<<NSB * SPLIT, 256, 0, stream>>>(fd, td, keys);
  resolve_k<<<NPIX / 256, 256, 0, stream>>>(vb, faces, keys, out_tex, out_img);
}